// Round 11
// baseline (49.633 us; speedup 1.0000x reference)
//
#include <hip/hip_runtime.h>
#include <hip/hip_bf16.h>
#include <stdint.h>

#define IN_F 2048
#define OUT_F 128
#define KD 32
#define NR 256
#define OC 2176          // IN_F + OUT_F
#define OD 4096          // OUT_F * KD
#define KS 4             // k-splits
#define STEPS 16         // 32-k steps per split

typedef __bf16 bf16x8 __attribute__((ext_vector_type(8)));
typedef __bf16 bf16x4 __attribute__((ext_vector_type(4)));
typedef float  f32x4  __attribute__((ext_vector_type(4)));

// ---------------------------------------------------------------------------
// Prep (256 blocks, verbatim R10): copy x -> out[:, 0:2048]; xb2 = bf16(x)
// in MFMA A-frag order: chunk q = (k0>>3)*256 + row holds x[row][k0..k0+8).
// ---------------------------------------------------------------------------
__global__ __launch_bounds__(256) void prep_kernel(const float* __restrict__ x,
                                                   float* __restrict__ out,
                                                   __bf16* __restrict__ xb2) {
    const int q   = blockIdx.x * 256 + threadIdx.x;   // 0..65535
    const int row = q & 255;
    const int k0  = (q >> 8) << 3;
    const float* src = &x[row * IN_F + k0];
    float4 v0 = *reinterpret_cast<const float4*>(src);
    float4 v1 = *reinterpret_cast<const float4*>(src + 4);
    *reinterpret_cast<float4*>(&out[row * OC + k0])     = v0;
    *reinterpret_cast<float4*>(&out[row * OC + k0 + 4]) = v1;
    bf16x8 p = { (__bf16)v0.x, (__bf16)v0.y, (__bf16)v0.z, (__bf16)v0.w,
                 (__bf16)v1.x, (__bf16)v1.y, (__bf16)v1.z, (__bf16)v1.w };
    *reinterpret_cast<bf16x8*>(&xb2[(size_t)q * 8]) = p;
}

// ---------------------------------------------------------------------------
// GEMM (verbatim R10): Mt[ks][o][n] = sum_k x[n][k]*T[k][o]. T read once.
// grid (128 o-tiles, 4 ks) = 512 blocks; block tile 256n x 32o x 512k.
// ---------------------------------------------------------------------------
struct ASet { bf16x8 m[4]; };

__global__ __launch_bounds__(256, 4) void gemm_kernel(const __bf16* __restrict__ xb2,
                                                      const float* __restrict__ Tm,
                                                      float* __restrict__ Mt) {
    __shared__ __bf16 Bs[2][32][40];

    const int tid  = threadIdx.x;
    const int lane = tid & 63;
    const int wid  = tid >> 6;
    const int fr   = lane & 15, fg = lane >> 4;
    const int o0   = blockIdx.x * 32;
    const int ks   = blockIdx.y;
    const int n0   = wid * 64;
    const int h0   = ks * STEPS;

    float* dst = Mt + (size_t)ks * OD * NR;

    const int ow = tid & 31;
    const int k4 = (tid >> 5) << 2;
    const float* tb = Tm + (size_t)(ks * 512 + k4) * OD + o0 + ow;
    const __bf16* ab = xb2 + (((size_t)h0 * 4 + fg) * 256 + n0 + fr) * 8;

    f32x4 acc[4][2] = {};

#define LOADB(t) ({ const float* s_ = tb + (size_t)(t) * 32 * OD;            \
                    float4 p_; p_.x = s_[0]; p_.y = s_[OD];                  \
                    p_.z = s_[2 * OD]; p_.w = s_[3 * OD]; p_; })
#define WRITEB(buf, p) do {                                                  \
        bf16x4 v_ = { (__bf16)(p).x, (__bf16)(p).y, (__bf16)(p).z, (__bf16)(p).w }; \
        *reinterpret_cast<bf16x4*>(&Bs[buf][ow][k4]) = v_; } while (0)

    auto LOADASET = [&](int t) {
        ASet a;
        #pragma unroll
        for (int mi = 0; mi < 4; ++mi)
            a.m[mi] = *reinterpret_cast<const bf16x8*>(ab + (size_t)t * 8192 + mi * 128);
        return a;
    };

    float4 p1, p2;
    {
        float4 p0 = LOADB(0);
        p1 = LOADB(1);
        p2 = LOADB(2);
        WRITEB(0, p0);
    }
    ASet a0 = LOADASET(0);
    ASet a1 = LOADASET(1);

    asm volatile("s_waitcnt lgkmcnt(0)" ::: "memory");
    __builtin_amdgcn_s_barrier();
    asm volatile("" ::: "memory");

    for (int t = 0; t < STEPS; ++t) {
        const int buf = t & 1;
        bf16x8 b0 = *reinterpret_cast<const bf16x8*>(&Bs[buf][fr][fg * 8]);
        bf16x8 b1 = *reinterpret_cast<const bf16x8*>(&Bs[buf][16 + fr][fg * 8]);
        #pragma unroll
        for (int mi = 0; mi < 4; ++mi) {
            acc[mi][0] = __builtin_amdgcn_mfma_f32_16x16x32_bf16(a0.m[mi], b0, acc[mi][0], 0, 0, 0);
            acc[mi][1] = __builtin_amdgcn_mfma_f32_16x16x32_bf16(a0.m[mi], b1, acc[mi][1], 0, 0, 0);
        }
        if (t < STEPS - 1) {
            WRITEB(buf ^ 1, p1);
            p1 = p2;
            if (t + 3 < STEPS) p2 = LOADB(t + 3);
            a0 = a1;
            if (t + 2 < STEPS) a1 = LOADASET(t + 2);
            asm volatile("s_waitcnt lgkmcnt(0)" ::: "memory");
            __builtin_amdgcn_s_barrier();
            asm volatile("" ::: "memory");
        }
    }
#undef LOADB
#undef WRITEB

    #pragma unroll
    for (int mi = 0; mi < 4; ++mi) {
        #pragma unroll
        for (int oi = 0; oi < 2; ++oi) {
            const int o = o0 + oi * 16 + fr;
            *reinterpret_cast<f32x4*>(&dst[(size_t)o * NR + n0 + mi * 16 + fg * 4]) = acc[mi][oi];
        }
    }
}

// ---------------------------------------------------------------------------
// Finale (fused p8t + pairwise; 128 blocks, one per f, 256 thr):
//  thread t owns row n = j = t. Stage: merge 4 partials -> tmp[32] (regs)
//  + Mf LDS (for the rare exact path). Projections: 4 Walsh sign-projections
//  (masks 1,2,4,8) per row; distributed across lanes as 4x f32x4; screen loop
//  fetches the i-side via v_readlane (wave-uniform index) -> ZERO memory
//  traffic in the hot loop. Skip pair when max_p |dproj| > 64 (=> L1 > 64 =>
//  exp == 0.0f even after bf16-GEMM margin). Diagonal analytic (+1).
// ---------------------------------------------------------------------------
__device__ __forceinline__ float rdlane(float v, int l) {
    return __builtin_bit_cast(float, __builtin_amdgcn_readlane(__builtin_bit_cast(int, v), l));
}

__global__ __launch_bounds__(256, 4) void finale_kernel(const float* __restrict__ Mt,
                                                        float* __restrict__ out) {
    __shared__ float Mf[256][33];
    __shared__ float P4[256][4];

    const int f    = blockIdx.x;
    const int t    = threadIdx.x;        // = j = n
    const int lane = t & 63;

    // merge 4 split-K partials; coalesced (consecutive t -> consecutive addr)
    float tmp[32];
    #pragma unroll
    for (int d = 0; d < 32; ++d) {
        float v = 0.f;
        #pragma unroll
        for (int s = 0; s < KS; ++s)
            v += Mt[(size_t)s * OD * NR + (f * KD + d) * NR + t];
        tmp[d] = v;
    }
    #pragma unroll
    for (int d4 = 0; d4 < 8; ++d4) {
        f32x4 w = { tmp[d4 * 4], tmp[d4 * 4 + 1], tmp[d4 * 4 + 2], tmp[d4 * 4 + 3] };
        *reinterpret_cast<f32x4*>(&Mf[t][d4 * 4]) = w;
    }

    // 4 Walsh projections of own row
    float pr0 = 0.f, pr1 = 0.f, pr2 = 0.f, pr3 = 0.f;
    #pragma unroll
    for (int d = 0; d < 32; ++d) {
        const float v = tmp[d];
        pr0 += (d & 1) ? -v : v;
        pr1 += (d & 2) ? -v : v;
        pr2 += (d & 4) ? -v : v;
        pr3 += (d & 8) ? -v : v;
    }
    {
        f32x4 w = { pr0, pr1, pr2, pr3 };
        *reinterpret_cast<f32x4*>(&P4[t][0]) = w;
    }
    __syncthreads();

    // distribute projections: quad c holds P4[c*64 + lane]
    f32x4 q0 = *reinterpret_cast<const f32x4*>(&P4[0 * 64 + lane][0]);
    f32x4 q1 = *reinterpret_cast<const f32x4*>(&P4[1 * 64 + lane][0]);
    f32x4 q2 = *reinterpret_cast<const f32x4*>(&P4[2 * 64 + lane][0]);
    f32x4 q3 = *reinterpret_cast<const f32x4*>(&P4[3 * 64 + lane][0]);

    float acc = 1.0f;    // diagonal term exp(0)=1, exact

#define SCREEN_CHUNK(Q, C)                                                     \
    for (int ii = 0; ii < 64; ++ii) {                                          \
        const int i = (C) * 64 + ii;            /* wave-uniform */             \
        const float s0 = rdlane((Q)[0], ii);                                   \
        const float s1 = rdlane((Q)[1], ii);                                   \
        const float s2 = rdlane((Q)[2], ii);                                   \
        const float s3 = rdlane((Q)[3], ii);                                   \
        const float mx = fmaxf(fmaxf(fabsf(s0 - pr0), fabsf(s1 - pr1)),        \
                               fmaxf(fabsf(s2 - pr2), fabsf(s3 - pr3)));       \
        const bool ok = (mx < 64.f) && (i != t);                               \
        if (__builtin_expect(__any(ok), 0)) {                                  \
            if (ok) {                                                          \
                float norm = 0.f;                                              \
                _Pragma("unroll")                                              \
                for (int d4 = 0; d4 < 8; ++d4) {                               \
                    f32x4 a = *reinterpret_cast<const f32x4*>(&Mf[i][d4 * 4]); \
                    norm += fabsf(a[0] - tmp[d4 * 4])                          \
                          + fabsf(a[1] - tmp[d4 * 4 + 1])                      \
                          + fabsf(a[2] - tmp[d4 * 4 + 2])                      \
                          + fabsf(a[3] - tmp[d4 * 4 + 3]);                     \
                }                                                              \
                acc += __expf(-norm);                                          \
            }                                                                  \
        }                                                                      \
    }

    SCREEN_CHUNK(q0, 0)
    SCREEN_CHUNK(q1, 1)
    SCREEN_CHUNK(q2, 2)
    SCREEN_CHUNK(q3, 3)
#undef SCREEN_CHUNK

    out[t * OC + IN_F + f] = acc;
}

extern "C" void kernel_launch(void* const* d_in, const int* in_sizes, int n_in,
                              void* d_out, int out_size, void* d_ws, size_t ws_size,
                              hipStream_t stream) {
    const float* x  = (const float*)d_in[0];   // [256, 2048] f32
    const float* Tm = (const float*)d_in[1];   // [2048, 4096] f32
    float* out = (float*)d_out;                // [256, 2176] f32
    char*  ws  = (char*)d_ws;

    float*  Mt  = (float*)ws;                     // 16 MB: 4 f32 o-major partials
    __bf16* xb2 = (__bf16*)(ws + (16u << 20));    // 1 MB A-frag image of x

    prep_kernel<<<dim3(256), 256, 0, stream>>>(x, out, xb2);
    gemm_kernel<<<dim3(128, KS), 256, 0, stream>>>(xb2, Tm, Mt);
    finale_kernel<<<dim3(128), 256, 0, stream>>>(Mt, out);
}

// Round 12
// 44.561 us; speedup vs baseline: 1.1138x; 1.1138x over previous
//
#include <hip/hip_runtime.h>
#include <hip/hip_bf16.h>
#include <stdint.h>

#define IN_F 2048
#define OUT_F 128
#define KD 32
#define NR 256
#define OC 2176          // IN_F + OUT_F
#define OD 4096          // OUT_F * KD
#define KSN 8            // k-splits
#define STEPS 8          // 32-k steps per split (256 k per block)

typedef __bf16 bf16x8 __attribute__((ext_vector_type(8)));
typedef __bf16 bf16x4 __attribute__((ext_vector_type(4)));
typedef float  f32x4  __attribute__((ext_vector_type(4)));
typedef uint16_t u16x8 __attribute__((ext_vector_type(8)));

#define A_BYTES 131072           // 32 chunks x 256 n x 16 B (frag image slice)
#define B_ROW   36               // bf16 per Bs row (72 B: b64-aligned, 16-bank spread)
#define B_BYTES (128 * B_ROW * 2)       // 9216 per buffer
#define LDS_TOTAL (A_BYTES + 2 * B_BYTES)  // 149504

// ---------------------------------------------------------------------------
// Prep (verbatim R10): copy x -> out[:, 0:2048]; xb2 = bf16(x) in MFMA A-frag
// order: chunk q = (k0>>3)*256 + row holds x[row][k0..k0+8).
// ---------------------------------------------------------------------------
__global__ __launch_bounds__(256) void prep_kernel(const float* __restrict__ x,
                                                   float* __restrict__ out,
                                                   __bf16* __restrict__ xb2) {
    const int q   = blockIdx.x * 256 + threadIdx.x;   // 0..65535
    const int row = q & 255;
    const int k0  = (q >> 8) << 3;
    const float* src = &x[row * IN_F + k0];
    float4 v0 = *reinterpret_cast<const float4*>(src);
    float4 v1 = *reinterpret_cast<const float4*>(src + 4);
    *reinterpret_cast<float4*>(&out[row * OC + k0])     = v0;
    *reinterpret_cast<float4*>(&out[row * OC + k0 + 4]) = v1;
    bf16x8 p = { (__bf16)v0.x, (__bf16)v0.y, (__bf16)v0.z, (__bf16)v0.w,
                 (__bf16)v1.x, (__bf16)v1.y, (__bf16)v1.z, (__bf16)v1.w };
    *reinterpret_cast<bf16x8*>(&xb2[(size_t)q * 8]) = p;
}

// ---------------------------------------------------------------------------
// GEMM: Mtb[ks][o][n] (bf16) = partial sum over k-slice. 256 blocks =
// (32 o-chunks x 8 ks), 512 thr = 8 waves (4 n-groups x 2 o-groups).
// A-slice (128 KB frag image) LDS-resident via global_load_lds (linear).
// B: per step stage T 32k x 128o f32 -> transposed bf16 Bs[o][k] (dbuf).
// Swapped MFMA: mfma(Bfrag, Afrag) -> D[o][n]; epilogue n-contiguous bf16.
// XCD note: block b = o*8+ks -> b%8 = ks: all blocks sharing an A-slice land
// on one XCD's L2 (ideal reuse).
// ---------------------------------------------------------------------------
__global__ __launch_bounds__(512, 2) void gemm_kernel(const __bf16* __restrict__ xb2,
                                                      const float* __restrict__ Tm,
                                                      __bf16* __restrict__ Mtb) {
    extern __shared__ char smem[];
    char* bsm = smem + A_BYTES;

    const int tid  = threadIdx.x;
    const int lane = tid & 63;
    const int wid  = tid >> 6;           // 0..7
    const int wn   = wid >> 1;           // 0..3: n-base wn*64
    const int wo   = wid & 1;            // 0..1: o-base wo*64
    const int fr   = lane & 15, fg = lane >> 4;
    const int b    = blockIdx.x;
    const int bo   = b >> 3;             // 0..31 o-chunk
    const int ks   = b & 7;
    const int o0   = bo * 128;

    // ---- A-image stage: contiguous 128 KB slice of xb2 (linear copy)
    {
        const char* g = (const char*)xb2 + (size_t)ks * A_BYTES;
        #pragma unroll
        for (int i = 0; i < 16; ++i) {
            const int off = i * 8192 + tid * 16;
            __builtin_amdgcn_global_load_lds(
                (const __attribute__((address_space(1))) uint32_t*)(g + off),
                (__attribute__((address_space(3))) uint32_t*)(smem + off), 16, 0, 0);
        }
    }

    // ---- B staging map: thread -> (o = tid&127, k-rows kq*8..+8)
    const int ow = tid & 127;
    const int kq = tid >> 7;             // 0..3
    const float* tb = Tm + (size_t)(ks * 256 + kq * 8) * OD + o0 + ow;

    float rA[8], rB[8];

#define ISSUEB(dst, t) do {                                                   \
        _Pragma("unroll")                                                     \
        for (int i_ = 0; i_ < 8; ++i_)                                        \
            dst[i_] = tb[(size_t)(t) * 32 * OD + (size_t)i_ * OD];            \
    } while (0)
#define WRITEB(bufc, src) do {                                                \
        char* base_ = bsm + (bufc) * B_BYTES + ow * (B_ROW * 2) + kq * 16;    \
        _Pragma("unroll")                                                     \
        for (int i_ = 0; i_ < 4; ++i_) {                                      \
            __bf16 lo_ = (__bf16)src[2 * i_], hi_ = (__bf16)src[2 * i_ + 1];  \
            uint32_t w_ = (uint32_t)__builtin_bit_cast(uint16_t, lo_)         \
                        | ((uint32_t)__builtin_bit_cast(uint16_t, hi_) << 16);\
            *(uint32_t*)(base_ + i_ * 4) = w_;                                \
        }                                                                     \
    } while (0)

    f32x4 acc[2][4][4] = {};   // [wo-unused dim folded: [oi][mi]] -> use [1]..

    // actually: acc[oi][mi], oi 0..3 (o-tiles of 16 in wave's 64), mi 0..3
    // (typed above with an extra dim to keep static indexing; use acc[0]/acc[1]? no:)
#define ACC(oi, mi) acc[0][oi][mi]

    ISSUEB(rA, 0);                       // B0
    ISSUEB(rB, 1);                       // B1
    asm volatile("s_waitcnt vmcnt(0)" ::: "memory");   // A image + B0 done
    WRITEB(0, rA);
    __syncthreads();

#define BFRAG(buf, t_oi, bfout) do {                                          \
        const char* p_ = bsm + (buf) * B_BYTES                                \
                       + (wo * 64 + (t_oi) * 16 + fr) * (B_ROW * 2) + fg * 16;\
        bf16x4 lo_ = *(const bf16x4*)p_;                                      \
        bf16x4 hi_ = *(const bf16x4*)(p_ + 8);                                \
        bfout = __builtin_shufflevector(lo_, hi_, 0, 1, 2, 3, 4, 5, 6, 7);    \
    } while (0)
#define AFRAG(t, mi) (*(const bf16x8*)(smem + ((t) * 4 + fg) * 4096           \
                       + (wn * 64 + (mi) * 16 + fr) * 16))

#define COMPUTE(t, buf) do {                                                  \
        bf16x8 bf_[4]; bf16x8 af_[4];                                         \
        _Pragma("unroll") for (int oi_ = 0; oi_ < 4; ++oi_) BFRAG(buf, oi_, bf_[oi_]); \
        _Pragma("unroll") for (int mi_ = 0; mi_ < 4; ++mi_) af_[mi_] = AFRAG(t, mi_);  \
        _Pragma("unroll") for (int oi_ = 0; oi_ < 4; ++oi_)                   \
        _Pragma("unroll") for (int mi_ = 0; mi_ < 4; ++mi_)                   \
            ACC(oi_, mi_) = __builtin_amdgcn_mfma_f32_16x16x32_bf16(          \
                bf_[oi_], af_[mi_], ACC(oi_, mi_), 0, 0, 0);                  \
    } while (0)

#define BAR() do { asm volatile("s_waitcnt lgkmcnt(0)" ::: "memory");         \
                   __builtin_amdgcn_s_barrier();                              \
                   asm volatile("" ::: "memory"); } while (0)

    #pragma unroll
    for (int tt = 0; tt < 4; ++tt) {
        const int t0 = tt * 2, t1 = tt * 2 + 1;
        // even step: compute buf0 (B[t0]); write B[t0+1] -> buf1
        if (t0 + 2 < STEPS) ISSUEB(rA, t0 + 2);
        COMPUTE(t0, 0);
        BAR();
        WRITEB(1, rB);
        BAR();
        // odd step: compute buf1 (B[t1]); write B[t1+1] -> buf0
        if (t1 + 2 < STEPS) ISSUEB(rB, t1 + 2);
        COMPUTE(t1, 1);
        BAR();
        if (t1 + 1 < STEPS) WRITEB(0, rA);
        BAR();
    }
#undef ISSUEB
#undef WRITEB
#undef BFRAG
#undef AFRAG
#undef COMPUTE
#undef BAR

    // epilogue: D[row=o_local][col=n_local]; row = fg*4+r, col = fr.
    __bf16* dstp = Mtb + (size_t)ks * OD * NR;
    #pragma unroll
    for (int oi = 0; oi < 4; ++oi) {
        #pragma unroll
        for (int mi = 0; mi < 4; ++mi) {
            const int n = wn * 64 + mi * 16 + fr;
            #pragma unroll
            for (int r = 0; r < 4; ++r) {
                const int o = o0 + wo * 64 + oi * 16 + fg * 4 + r;
                dstp[(size_t)o * NR + n] = (__bf16)ACC(oi, mi)[r];
            }
        }
    }
#undef ACC
}

// ---------------------------------------------------------------------------
// P8T (256 blocks = 128 f x 2 n-halves, 256 thr): merge 8 bf16 partials
// (vectorized ushort8 reads), write Mn2 (f-major merged f32, coalesced) and
// 8 Walsh sign-projections P8f[f][n][8]. Soundness: L1(v) >= |<eps,v>|.
// ---------------------------------------------------------------------------
__global__ __launch_bounds__(256) void p8t_kernel(const __bf16* __restrict__ Mtb,
                                                  float* __restrict__ Mn2,
                                                  float* __restrict__ P8f) {
    __shared__ float tr[32][132];        // [d][n-local], pad 132 (16B-aligned rows)

    const int f  = blockIdx.x >> 1;
    const int nh = blockIdx.x & 1;
    const int t  = threadIdx.x;

    #pragma unroll
    for (int p = 0; p < 2; ++p) {
        const int d   = p * 16 + (t >> 4);        // 0..31
        const int oct = t & 15;                   // 16 octs x 8 n = 128 n
        const int nl  = oct * 8;                  // n-local
        const size_t base = ((size_t)(f * KD + d)) * NR + nh * 128 + nl;
        float a[8] = {};
        #pragma unroll
        for (int s = 0; s < KSN; ++s) {
            u16x8 v = *reinterpret_cast<const u16x8*>(
                reinterpret_cast<const uint16_t*>(Mtb) + (size_t)s * OD * NR + base);
            #pragma unroll
            for (int i = 0; i < 8; ++i)
                a[i] += __builtin_bit_cast(float, (uint32_t)v[i] << 16);
        }
        f32x4 w0 = { a[0], a[1], a[2], a[3] };
        f32x4 w1 = { a[4], a[5], a[6], a[7] };
        *reinterpret_cast<f32x4*>(Mn2 + base)     = w0;
        *reinterpret_cast<f32x4*>(Mn2 + base + 4) = w1;
        *reinterpret_cast<f32x4*>(&tr[d][nl])     = w0;
        *reinterpret_cast<f32x4*>(&tr[d][nl + 4]) = w1;
    }
    __syncthreads();

    if (t < 128) {
        const int n = nh * 128 + t;
        const int MK[8] = { 0, 1, 2, 4, 8, 16, 3, 24 };
        float pr[8] = {};
        #pragma unroll
        for (int d = 0; d < 32; ++d) {
            const float v = tr[d][t];
            #pragma unroll
            for (int p = 0; p < 8; ++p)
                pr[p] += (__popc(d & MK[p]) & 1) ? -v : v;
        }
        f32x4 w0 = { pr[0], pr[1], pr[2], pr[3] };
        f32x4 w1 = { pr[4], pr[5], pr[6], pr[7] };
        float* dst = P8f + ((size_t)f * NR + n) * 8;
        *reinterpret_cast<f32x4*>(dst)     = w0;
        *reinterpret_cast<f32x4*>(dst + 4) = w1;
    }
}

// ---------------------------------------------------------------------------
// Pairwise (R10-proven screened form): o_b[j,f] = 1 + sum_{i!=j} exp(-L1).
// Screen: skip when max_p |proj_p(i)-proj_p(j)| > 64 (term <= e^-49 after
// margins -> exactly 0.0f). Survivors (~1e-7) get exact f32 norm from Mn2.
// grid (128 f, 4 jq), 256 thr; wave wid owns i in [wid*64,+64).
// ---------------------------------------------------------------------------
__global__ __launch_bounds__(256, 2) void pairwise_kernel(const float* __restrict__ P8f,
                                                          const float* __restrict__ Mn2,
                                                          float* __restrict__ out) {
    __shared__ float part[4][64];

    const int f    = blockIdx.x;
    const int jq   = blockIdx.y;
    const int tid  = threadIdx.x;
    const int lane = tid & 63;
    const int wid  = tid >> 6;
    const int j    = jq * 64 + lane;

    const float* pjp = P8f + ((size_t)f * NR + j) * 8;
    const f32x4 pj0 = *reinterpret_cast<const f32x4*>(pjp);
    const f32x4 pj1 = *reinterpret_cast<const f32x4*>(pjp + 4);

    const float* bp = P8f + (size_t)f * NR * 8;
    const int i0 = wid * 64;

    float acc = 0.f;
    #pragma unroll 2
    for (int ii = 0; ii < 64; ++ii) {
        const int i = i0 + ii;
        const float* rp = bp + (size_t)i * 8;
        f32x4 q0 = *reinterpret_cast<const f32x4*>(rp);
        f32x4 q1 = *reinterpret_cast<const f32x4*>(rp + 4);
        f32x4 d0 = q0 - pj0;
        f32x4 d1 = q1 - pj1;
        float m0 = fmaxf(fmaxf(fabsf(d0[0]), fabsf(d0[1])), fabsf(d0[2]));
        float m1 = fmaxf(fmaxf(fabsf(d0[3]), fabsf(d1[0])), fabsf(d1[1]));
        float m2 = fmaxf(fabsf(d1[2]), fabsf(d1[3]));
        const float mx = fmaxf(fmaxf(m0, m1), m2);

        const bool ok = (mx < 64.f) && (i != j);
        if (__builtin_expect(__any(ok), 0)) {
            if (ok) {
                float norm = 0.f;
                #pragma unroll
                for (int d = 0; d < 32; ++d) {
                    const float* row = Mn2 + (size_t)(f * KD + d) * NR;
                    norm += fabsf(row[i] - row[j]);
                }
                acc += __expf(-norm);
            }
        }
    }

    if (wid == jq) acc += 1.0f;          // diagonal exp(0)=1, exact

    part[wid][lane] = acc;
    __syncthreads();
    if (tid < 64) {
        float s = part[0][tid] + part[1][tid] + part[2][tid] + part[3][tid];
        out[(jq * 64 + tid) * OC + IN_F + f] = s;
    }
}

extern "C" void kernel_launch(void* const* d_in, const int* in_sizes, int n_in,
                              void* d_out, int out_size, void* d_ws, size_t ws_size,
                              hipStream_t stream) {
    const float* x  = (const float*)d_in[0];   // [256, 2048] f32
    const float* Tm = (const float*)d_in[1];   // [2048, 4096] f32
    float* out = (float*)d_out;                // [256, 2176] f32
    char*  ws  = (char*)d_ws;

    __bf16* Mtb = (__bf16*)ws;                      // 16 MB: 8 bf16 o-major partials
    __bf16* xb2 = (__bf16*)(ws + (16u << 20));      // 1 MB A-frag image of x
    float*  Mn2 = (float*)(ws + (17u << 20));       // 4 MB f-major merged M
    float*  P8f = (float*)(ws + (21u << 20));       // 1 MB f32 projections

    prep_kernel<<<dim3(256), 256, 0, stream>>>(x, out, xb2);
    gemm_kernel<<<dim3(256), 512, LDS_TOTAL, stream>>>(xb2, Tm, Mtb);
    p8t_kernel<<<dim3(256), 256, 0, stream>>>(Mtb, Mn2, P8f);
    pairwise_kernel<<<dim3(128, 4), 256, 0, stream>>>(P8f, Mn2, out);
}

// Round 13
// 34.101 us; speedup vs baseline: 1.4555x; 1.3067x over previous
//
#include <hip/hip_runtime.h>
#include <hip/hip_bf16.h>
#include <stdint.h>

#define IN_F 2048
#define OUT_F 128
#define KD 32
#define NR 256
#define OC 2176          // IN_F + OUT_F
#define OD 4096          // OUT_F * KD (T row stride)
#define OP 1024          // OUT_F * 8 projections
#define THRESH 32.0f

typedef __bf16 bf16x8 __attribute__((ext_vector_type(8)));
typedef float  f32x4  __attribute__((ext_vector_type(4)));

// Walsh sign masks for p=0..7, packed 5 bits each: {0,1,2,4,8,16,3,24}
#define MASK_PACK (0ull | (1ull<<5) | (2ull<<10) | (4ull<<15) | (8ull<<20) | \
                   (16ull<<25) | (3ull<<30) | (24ull<<35))

// ---------------------------------------------------------------------------
// tproj (1280 blocks): bid<1024: Tb = bf16 B-frag image of Tproj, where
//   Tproj[k][o'=f*8+p] = sum_d sign_p(d) * T[k][f][d]  (d-contiguous reads).
//   Image: chunk c = kt*64 + ot (kt=k/32, ot=o'/16); lane l=(fg=l>>4,fr=l&15)
//   holds Tproj[kt*32+fg*8+i][ot*16+fr] i=0..7 at Tb + (c*64+l)*8 elems.
// bid>=1024: prep verbatim (x -> out copy + xb2 A-frag image).
// ---------------------------------------------------------------------------
__global__ __launch_bounds__(256) void tproj_kernel(const float* __restrict__ x,
                                                    const float* __restrict__ Tm,
                                                    float* __restrict__ out,
                                                    __bf16* __restrict__ xb2,
                                                    __bf16* __restrict__ Tb) {
    const int bid = blockIdx.x;
    if (bid < 1024) {
        const int u  = bid * 256 + threadIdx.x;   // 0..262143
        const int l  = u & 63;
        const int c  = u >> 6;                    // 0..4095
        const int ot = c & 63;
        const int kt = c >> 6;                    // 0..63
        const int fr = l & 15, fg = l >> 4;
        const int f  = ot * 2 + (fr >> 3);
        const int p  = fr & 7;
        const uint32_t mask = (uint32_t)((MASK_PACK >> (p * 5)) & 31u);

        float smul[32];
        #pragma unroll
        for (int d = 0; d < 32; ++d)
            smul[d] = __builtin_bit_cast(float,
                0x3f800000u | ((uint32_t)(__popc(d & mask) & 1) << 31));

        const float* src0 = Tm + (size_t)(kt * 32 + fg * 8) * OD + f * KD;
        bf16x8 pk;
        #pragma unroll
        for (int i = 0; i < 8; ++i) {
            const float* row = src0 + (size_t)i * OD;
            float s = 0.f;
            #pragma unroll
            for (int q = 0; q < 8; ++q) {
                f32x4 v = *reinterpret_cast<const f32x4*>(row + q * 4);
                s += smul[q*4]*v[0] + smul[q*4+1]*v[1]
                   + smul[q*4+2]*v[2] + smul[q*4+3]*v[3];
            }
            pk[i] = (__bf16)s;
        }
        *reinterpret_cast<bf16x8*>(Tb + (size_t)u * 8) = pk;
    } else {
        const int q   = (bid - 1024) * 256 + threadIdx.x;  // 0..65535
        const int row = q & 255;
        const int k0  = (q >> 8) << 3;
        const float* src = &x[row * IN_F + k0];
        float4 v0 = *reinterpret_cast<const float4*>(src);
        float4 v1 = *reinterpret_cast<const float4*>(src + 4);
        *reinterpret_cast<float4*>(&out[row * OC + k0])     = v0;
        *reinterpret_cast<float4*>(&out[row * OC + k0 + 4]) = v1;
        bf16x8 p = { (__bf16)v0.x, (__bf16)v0.y, (__bf16)v0.z, (__bf16)v0.w,
                     (__bf16)v1.x, (__bf16)v1.y, (__bf16)v1.z, (__bf16)v1.w };
        *reinterpret_cast<bf16x8*>(&xb2[(size_t)q * 8]) = p;
    }
}

// ---------------------------------------------------------------------------
// Screen-GEMM: Pp[ks][o'][n] (f32 partials) = x @ Tproj over k-slice ks.
// Barrier-free, LDS-free frag stream (R5 structure). 256 thr = 4 waves;
// wave tile 16n x 32o'. grid (32 o'-chunks, 4 n-tiles, 8 ks) = 1024 blocks
// = 4/CU. Per 32k half-step: 1 A + 2 B b128 loads -> 2 MFMA; 3-deep prefetch.
// ---------------------------------------------------------------------------
struct SFrag { bf16x8 a, b0, b1; };

__device__ __forceinline__ SFrag s_load(const __bf16* __restrict__ xb2,
                                        const __bf16* __restrict__ Tb,
                                        int h, int n0fr, int ot0, int l) {
    SFrag s;
    s.a = *reinterpret_cast<const bf16x8*>(xb2 + ((size_t)(h * 4 + (l >> 4)) * 256 + n0fr) * 8);
    const __bf16* bb = Tb + (((size_t)h * 64 + ot0) * 64 + l) * 8;
    s.b0 = *reinterpret_cast<const bf16x8*>(bb);
    s.b1 = *reinterpret_cast<const bf16x8*>(bb + 512);
    return s;
}

__global__ __launch_bounds__(256, 4) void sgemm_kernel(const __bf16* __restrict__ xb2,
                                                       const __bf16* __restrict__ Tb,
                                                       float* __restrict__ Pp) {
    const int tid = threadIdx.x;
    const int l   = tid & 63;
    const int wid = tid >> 6;
    const int fr  = l & 15, fg = l >> 4;
    const int co  = blockIdx.x;            // 0..31: o' chunk of 32
    const int bn  = blockIdx.y;            // 0..3 : n tile of 64
    const int ks  = blockIdx.z;            // 0..7 : k slice of 256
    const int ot0 = co * 2;
    const int n0  = bn * 64 + wid * 16;
    const int h0  = ks * 8;
    const int n0fr = n0 + fr;

    f32x4 acc0 = {}, acc1 = {};

#define CMP(s) do { \
        acc0 = __builtin_amdgcn_mfma_f32_16x16x32_bf16((s).a, (s).b0, acc0, 0, 0, 0); \
        acc1 = __builtin_amdgcn_mfma_f32_16x16x32_bf16((s).a, (s).b1, acc1, 0, 0, 0); \
    } while (0)

    SFrag s0 = s_load(xb2, Tb, h0 + 0, n0fr, ot0, l);
    SFrag s1 = s_load(xb2, Tb, h0 + 1, n0fr, ot0, l);
    SFrag s2 = s_load(xb2, Tb, h0 + 2, n0fr, ot0, l);

    CMP(s0); s0 = s_load(xb2, Tb, h0 + 3, n0fr, ot0, l);
    CMP(s1); s1 = s_load(xb2, Tb, h0 + 4, n0fr, ot0, l);
    CMP(s2); s2 = s_load(xb2, Tb, h0 + 5, n0fr, ot0, l);
    CMP(s0); s0 = s_load(xb2, Tb, h0 + 6, n0fr, ot0, l);
    CMP(s1); s1 = s_load(xb2, Tb, h0 + 7, n0fr, ot0, l);
    CMP(s2);
    CMP(s0);
    CMP(s1);
#undef CMP

    // epilogue: D[row=n][col=o']; lane: col=fr, rows=fg*4+r (verified mapping)
    float* dst = Pp + ((size_t)ks << 18);            // ks * OP * NR
    const int o0 = co * 32;
    const int nb = n0 + fg * 4;
    *reinterpret_cast<f32x4*>(&dst[(size_t)(o0 + fr)      * NR + nb]) = acc0;
    *reinterpret_cast<f32x4*>(&dst[(size_t)(o0 + 16 + fr) * NR + nb]) = acc1;
}

// ---------------------------------------------------------------------------
// Screen (R10-proven structure): o_b[j,f] = 1 + sum_{i!=j} exp(-L1).
// Stage merged projections (8 partials) into LDS; screen via max_p |dproj|;
// drop when > 32 (sound: L1 >= |dproj|; after +-10 bf16 margin, dropped
// terms <= 256*e^-22 ~ 7e-8 << 0.099). Rare survivor (~P 5e-3 total) gets
// exact norm computed on the fly from x and T. grid (128 f, 4 jq), 256 thr.
// ---------------------------------------------------------------------------
__global__ __launch_bounds__(256, 2) void screen_kernel(const float* __restrict__ Pp,
                                                        const float* __restrict__ x,
                                                        const float* __restrict__ Tm,
                                                        float* __restrict__ out) {
    __shared__ float P8s[256][8];
    __shared__ float part[4][64];

    const int f    = blockIdx.x;
    const int jq   = blockIdx.y;
    const int tid  = threadIdx.x;
    const int lane = tid & 63;
    const int wid  = tid >> 6;
    const int j    = jq * 64 + lane;

    // stage: merged projection row for n = tid (coalesced per (ks,p) pass)
    #pragma unroll
    for (int p = 0; p < 8; ++p) {
        float s = 0.f;
        #pragma unroll
        for (int ks = 0; ks < 8; ++ks)
            s += Pp[((size_t)ks << 18) + (size_t)(f * 8 + p) * NR + tid];
        P8s[tid][p] = s;
    }
    __syncthreads();

    const f32x4 qj0 = *reinterpret_cast<const f32x4*>(&P8s[j][0]);
    const f32x4 qj1 = *reinterpret_cast<const f32x4*>(&P8s[j][4]);

    float acc = 0.f;
    const int i0 = wid * 64;
    #pragma unroll 2
    for (int ii = 0; ii < 64; ++ii) {
        const int i = i0 + ii;                       // wave-uniform -> broadcast
        f32x4 r0 = *reinterpret_cast<const f32x4*>(&P8s[i][0]);
        f32x4 r1 = *reinterpret_cast<const f32x4*>(&P8s[i][4]);
        f32x4 d0 = r0 - qj0;
        f32x4 d1 = r1 - qj1;
        float m0 = fmaxf(fmaxf(fabsf(d0[0]), fabsf(d0[1])), fabsf(d0[2]));
        float m1 = fmaxf(fmaxf(fabsf(d0[3]), fabsf(d1[0])), fabsf(d1[1]));
        float m2 = fmaxf(fabsf(d1[2]), fabsf(d1[3]));
        const float mx = fmaxf(fmaxf(m0, m1), m2);

        const bool ok = (mx < THRESH) && (i != j);
        if (__builtin_expect(__any(ok), 0)) {
            if (ok) {
                // exact fallback: norm = sum_d |sum_k (x_i - x_j)_k * T[k][f][d]|
                f32x4 ad[8] = {};
                const float* xi = x + (size_t)i * IN_F;
                const float* xj = x + (size_t)j * IN_F;
                for (int k = 0; k < IN_F; ++k) {
                    const float dk = xi[k] - xj[k];
                    const float* tr = Tm + (size_t)k * OD + f * KD;
                    #pragma unroll
                    for (int q = 0; q < 8; ++q) {
                        f32x4 tv = *reinterpret_cast<const f32x4*>(tr + q * 4);
                        ad[q] += dk * tv;
                    }
                }
                float norm = 0.f;
                #pragma unroll
                for (int q = 0; q < 8; ++q)
                    norm += fabsf(ad[q][0]) + fabsf(ad[q][1])
                          + fabsf(ad[q][2]) + fabsf(ad[q][3]);
                acc += __expf(-norm);
            }
        }
    }

    if (wid == jq) acc += 1.0f;          // diagonal exp(0)=1, exact

    part[wid][lane] = acc;
    __syncthreads();
    if (tid < 64) {
        float s = part[0][tid] + part[1][tid] + part[2][tid] + part[3][tid];
        out[(jq * 64 + tid) * OC + IN_F + f] = s;
    }
}

extern "C" void kernel_launch(void* const* d_in, const int* in_sizes, int n_in,
                              void* d_out, int out_size, void* d_ws, size_t ws_size,
                              hipStream_t stream) {
    const float* x  = (const float*)d_in[0];   // [256, 2048] f32
    const float* Tm = (const float*)d_in[1];   // [2048, 4096] f32
    float* out = (float*)d_out;                // [256, 2176] f32
    char*  ws  = (char*)d_ws;

    __bf16* Tb  = (__bf16*)ws;                      // 4 MB  Tproj B-frag image
    __bf16* xb2 = (__bf16*)(ws + (4u << 20));       // 1 MB  x A-frag image
    float*  Pp  = (float*)(ws + (5u << 20));        // 8 MB  8 f32 o'-major partials

    tproj_kernel<<<dim3(1280), 256, 0, stream>>>(x, Tm, out, xb2, Tb);
    sgemm_kernel<<<dim3(32, 4, 8), 256, 0, stream>>>(xb2, Tb, Pp);
    screen_kernel<<<dim3(128, 4), 256, 0, stream>>>(Pp, x, Tm, out);
}